// Round 5
// baseline (73.301 us; speedup 1.0000x reference)
//
#include <hip/hip_runtime.h>

#define H 8
#define T_LEN 131072
#define CHUNK_L 64
#define WARM 128
#define NPAIR (T_LEN / CHUNK_L / 2)   // 1024 blocks; block b runs chunks b and b+NPAIR
#define SX_LEN 200                    // >= WARM+CHUNK_L+2, zero-padded

__device__ __forceinline__ float fast_rcp(float x) { return __builtin_amdgcn_rcpf(x); }
__device__ __forceinline__ float exp2_f(float x) {
#if __has_builtin(__builtin_amdgcn_exp2f)
    return __builtin_amdgcn_exp2f(x);
#else
    return exp2f(x);
#endif
}
__device__ __forceinline__ float bcast(float v, int lane) {   // v_readlane -> SGPR
    return __int_as_float(__builtin_amdgcn_readlane(__float_as_int(v), lane));
}
// broadcast quad-lane Q's value to all 4 lanes of each quad (DPP quad_perm, VALU pipe)
template<int Q>
__device__ __forceinline__ float quad_bcast(float v) {
    return __int_as_float(__builtin_amdgcn_update_dpp(
        0, __float_as_int(v), Q * 0x55, 0xf, 0xf, true));
}

// One wave runs TWO chunks (b and b+NPAIR) interleaved: weights are shared, each
// chunk has its own state reg. Lane = unit*4 + role; unit = layer*8+k; role
// 0:r 1:z 2:n-input 3:n-hidden. Gate rows pre-scaled: r,z by -log2(e), n by
// 2*log2(e), so sigmoid = rcp(1+exp2(a)), tanh = 1-2*rcp(1+exp2(r*anh+ani)) --
// 4 transcendentals/step, no muls. Roles specialize: lanes 0,1 compute the two
// sigmoids in one shared stream, lane 2 the tanh; quad_perm DPP redistributes.
__global__ __launch_bounds__(64, 1) void gru_chunk_kernel(
    const float* __restrict__ x, const float* __restrict__ hinit,
    const float* __restrict__ wih0, const float* __restrict__ whh0,
    const float* __restrict__ bih0, const float* __restrict__ bhh0,
    const float* __restrict__ wih1, const float* __restrict__ whh1,
    const float* __restrict__ bih1, const float* __restrict__ bhh1,
    const float* __restrict__ wlin, const float* __restrict__ blin,
    float* __restrict__ out)
{
    const int b = blockIdx.x;
    const int tid = threadIdx.x;
    const int sub = tid >> 2;        // unit 0..15
    const int role = tid & 3;        // r / z / n-input / n-hidden
    const int layer = sub >> 3;
    const int k = sub & 7;

    // per-chunk schedules (A = b, B = b + NPAIR; B is always a "regular" chunk)
    const int cA = b, cB = b + NPAIR;
    int tfA = cA * CHUNK_L - WARM; if (tfA < 0) tfA = 0;
    const int nsA = cA * CHUNK_L + CHUNK_L - tfA;
    const int sk2A = (cA * CHUNK_L - tfA) + 2;
    const int sendA = nsA + 1;
    const int tfB = cB * CHUNK_L - WARM;
    const int nsB = WARM + CHUNK_L;
    const int sk2B = WARM + 2;
    const int sendB = nsB + 1;       // == WARM + CHUNK_L + 1 == 193

    // stage both x windows into LDS, zero-padded
    __shared__ float sxA[SX_LEN], sxB[SX_LEN];
    for (int i = tid; i < SX_LEN; i += 64) {
        sxA[i] = (i < nsA) ? x[tfA + i] : 0.0f;
        sxB[i] = (i < nsB) ? x[tfB + i] : 0.0f;
    }
    __syncthreads();

    // per-lane packed weight vector over S=[h0(0..7), h1(0..7)], x-weight, bias
    float W[16];
#pragma unroll
    for (int j = 0; j < 16; j++) W[j] = 0.0f;
    float wx = 0.0f, bias;

    if (role == 0) {            // r gate
        if (layer == 0) {
#pragma unroll
            for (int j = 0; j < 8; j++) W[j] = whh0[k * H + j];
            wx = wih0[k];
            bias = bih0[k] + bhh0[k];
        } else {
#pragma unroll
            for (int j = 0; j < 8; j++) {
                W[j]     = wih1[k * H + j];       // input side: y0 = S[0..7]
                W[8 + j] = whh1[k * H + j];       // hidden side: h1 = S[8..15]
            }
            bias = bih1[k] + bhh1[k];
        }
    } else if (role == 1) {     // z gate
        const int row = H + k;
        if (layer == 0) {
#pragma unroll
            for (int j = 0; j < 8; j++) W[j] = whh0[row * H + j];
            wx = wih0[row];
            bias = bih0[row] + bhh0[row];
        } else {
#pragma unroll
            for (int j = 0; j < 8; j++) {
                W[j]     = wih1[row * H + j];
                W[8 + j] = whh1[row * H + j];
            }
            bias = bih1[row] + bhh1[row];
        }
    } else if (role == 2) {     // n gate, input side
        const int row = 2 * H + k;
        if (layer == 0) {
            wx = wih0[row];                       // input is scalar x
            bias = bih0[row];
        } else {
#pragma unroll
            for (int j = 0; j < 8; j++) W[j] = wih1[row * H + j];
            bias = bih1[row];
        }
    } else {                    // n gate, hidden side
        const int row = 2 * H + k;
        if (layer == 0) {
#pragma unroll
            for (int j = 0; j < 8; j++) W[j] = whh0[row * H + j];
            bias = bhh0[row];
        } else {
#pragma unroll
            for (int j = 0; j < 8; j++) W[8 + j] = whh1[row * H + j];
            bias = bhh1[row];
        }
    }

    // fold the exp base conversion into the rows: r,z -> -log2(e); n -> 2*log2(e)
    {
        const float scale = (role < 2) ? -1.442695040888963f : 2.885390081777927f;
#pragma unroll
        for (int j = 0; j < 16; j++) W[j] *= scale;
        wx *= scale;
        bias *= scale;
    }

    float wl[8];
#pragma unroll
    for (int e = 0; e < 8; e++) wl[e] = wlin[e];
    const float bl = blin[0];

    float hvA = (tfA == 0) ? hinit[layer * H + k] : 0.0f;
    float hvB = 0.0f;
    float xvA = sxA[0], xvB = sxB[0];
    int s = 0;

    // One chunk-step. S-fill + readout hoisted by ordering below; dot+gates of A
    // and B land in the same basic block so the scheduler interleaves the chains.
#define CH_CORE(HV, XV, SX, SARR, GUARD)                                     \
    do {                                                                     \
        float xnext = (SX)[s + 1];                                           \
        float a0 = bias, a1 = 0.0f;                                          \
        _Pragma("unroll")                                                    \
        for (int j = 0; j < 8; j++) {                                        \
            a0 = fmaf(W[j], SARR[j], a0);                                    \
            a1 = fmaf(W[8 + j], SARR[8 + j], a1);                            \
        }                                                                    \
        float a = fmaf(wx, XV, a0 + a1);                                     \
        float eg = exp2_f(a);                                                \
        float g  = fast_rcp(1.0f + eg);      /* role0: r, role1: z */        \
        float rq   = quad_bcast<0>(g);                                       \
        float anhq = quad_bcast<3>(a);                                       \
        float tn = fmaf(rq, anhq, a);        /* role2: tanh input */         \
        float en = exp2_f(tn);                                               \
        float nn = fmaf(-2.0f, fast_rcp(1.0f + en), 1.0f);                   \
        float zq = quad_bcast<1>(g);                                         \
        float nq = quad_bcast<2>(nn);                                        \
        float hnew = fmaf(zq, (HV) - nq, nq);                                \
        if (GUARD) HV = (sub >= 8) ? (HV) : hnew; else HV = hnew;            \
        XV = xnext;                                                          \
    } while (0)

#define FULL_ITER(GUARD)                                                     \
    do {                                                                     \
        float SA[16], SB[16];                                                \
        _Pragma("unroll")                                                    \
        for (int j = 0; j < 16; j++) SA[j] = bcast(hvA, 4 * j);              \
        _Pragma("unroll")                                                    \
        for (int j = 0; j < 16; j++) SB[j] = bcast(hvB, 4 * j);              \
        if (s >= sk2A && s <= sendA) {                                       \
            float ov = bl;                                                   \
            _Pragma("unroll")                                                \
            for (int e = 0; e < 8; e++) ov = fmaf(wl[e], SA[8 + e], ov);     \
            if (tid == 0) out[tfA + s - 2] = ov;                             \
        }                                                                    \
        if (s >= sk2B && s <= sendB) {                                       \
            float ov = bl;                                                   \
            _Pragma("unroll")                                                \
            for (int e = 0; e < 8; e++) ov = fmaf(wl[e], SB[8 + e], ov);     \
            if (tid == 0) out[tfB + s - 2] = ov;                             \
        }                                                                    \
        CH_CORE(hvA, xvA, sxA, SA, GUARD);                                   \
        CH_CORE(hvB, xvB, sxB, SB, GUARD);                                   \
    } while (0)

    // s==0: layer1 holds its init (its y0 input not valid yet); harmless for
    // zero-init chunks, required for the true-init chunks (tf == 0).
    FULL_ITER(true);
    s++;
    const int send = WARM + CHUNK_L + 1;   // 193; A's stores self-bound by sendA
    for (; s <= send; s++) FULL_ITER(false);

#undef FULL_ITER
#undef CH_CORE
}

extern "C" void kernel_launch(void* const* d_in, const int* in_sizes, int n_in,
                              void* d_out, int out_size, void* d_ws, size_t ws_size,
                              hipStream_t stream) {
    (void)in_sizes; (void)n_in; (void)d_ws; (void)ws_size; (void)out_size;
    const float* x    = (const float*)d_in[0];
    const float* h0   = (const float*)d_in[1];
    const float* wih0 = (const float*)d_in[2];
    const float* whh0 = (const float*)d_in[3];
    const float* bih0 = (const float*)d_in[4];
    const float* bhh0 = (const float*)d_in[5];
    const float* wih1 = (const float*)d_in[6];
    const float* whh1 = (const float*)d_in[7];
    const float* bih1 = (const float*)d_in[8];
    const float* bhh1 = (const float*)d_in[9];
    const float* wlin = (const float*)d_in[10];
    const float* blin = (const float*)d_in[11];
    float* out = (float*)d_out;

    gru_chunk_kernel<<<NPAIR, 64, 0, stream>>>(
        x, h0, wih0, whh0, bih0, bhh0, wih1, whh1, bih1, bhh1, wlin, blin, out);
}

// Round 6
// 43.484 us; speedup vs baseline: 1.6857x; 1.6857x over previous
//
#include <hip/hip_runtime.h>

#define H 8
#define T_LEN 131072
#define CHUNK_L 64
#define WARM 128
#define NCHUNK (T_LEN / CHUNK_L)   // 2048 blocks -> 2 waves per SIMD
#define SX_LEN 200                 // >= WARM + CHUNK_L + 2, zero padded

__device__ __forceinline__ float fast_rcp(float x) { return __builtin_amdgcn_rcpf(x); }
__device__ __forceinline__ float exp2_f(float x) {
#if __has_builtin(__builtin_amdgcn_exp2f)
    return __builtin_amdgcn_exp2f(x);
#else
    return exp2f(x);
#endif
}
__device__ __forceinline__ float bcast(float v, int lane) {   // v_readlane -> SGPR
    return __int_as_float(__builtin_amdgcn_readlane(__float_as_int(v), lane));
}
// broadcast quad-lane Q's value to all 4 lanes of each quad (DPP quad_perm, VALU pipe)
template<int Q>
__device__ __forceinline__ float quad_bcast(float v) {
    return __int_as_float(__builtin_amdgcn_update_dpp(
        0, __float_as_int(v), Q * 0x55, 0xf, 0xf, true));
}

// One wave per chunk (2048 chunks -> 2 waves/SIMD hide each other's latency).
// Lane = unit*4 + role; unit = layer*8 + k; role 0:r 1:z 2:n-input 3:n-hidden.
// Gate rows pre-scaled (r,z by -log2e; n by 2*log2e): sigmoid = rcp(1+exp2(a)),
// tanh = 1-2*rcp(1+exp2(r*anh+ani)) -- 4 transcendentals/step. Weights are
// laundered through LDS (branchy init -> ds_write -> straight-line ds_read_b128)
// so they stay in VGPRs. Readout deferred: per-step state -> LDS history row,
// parallel epilogue computes out = wl . h1 + bl with coalesced stores.
__global__ __launch_bounds__(64, 2) void gru_chunk_kernel(
    const float* __restrict__ x, const float* __restrict__ hinit,
    const float* __restrict__ wih0, const float* __restrict__ whh0,
    const float* __restrict__ bih0, const float* __restrict__ bhh0,
    const float* __restrict__ wih1, const float* __restrict__ whh1,
    const float* __restrict__ bih1, const float* __restrict__ bhh1,
    const float* __restrict__ wlin, const float* __restrict__ blin,
    float* __restrict__ out)
{
    const int c = blockIdx.x;
    const int tid = threadIdx.x;
    const int sub = tid >> 2;        // unit 0..15
    const int role = tid & 3;        // r / z / n-input / n-hidden
    const int layer = sub >> 3;
    const int k = sub & 7;

    const int C = c * CHUNK_L;
    int t_first = C - WARM; if (t_first < 0) t_first = 0;
    const int skip = C - t_first;          // 0 (chunk 0) or WARM
    const int nsteps = skip + CHUNK_L;     // last step index

    __shared__ float sx[SX_LEN];
    __shared__ float Wbuf[64][16];
    __shared__ float hist[CHUNK_L][16];

    for (int i = tid; i < SX_LEN; i += 64)
        sx[i] = (i < nsteps) ? x[t_first + i] : 0.0f;

    // ---- branchy per-lane weight build (runs once) ----
    float W[16];
#pragma unroll
    for (int j = 0; j < 16; j++) W[j] = 0.0f;
    float wx = 0.0f, bias;

    if (role == 0) {            // r gate
        if (layer == 0) {
#pragma unroll
            for (int j = 0; j < 8; j++) W[j] = whh0[k * H + j];
            wx = wih0[k];
            bias = bih0[k] + bhh0[k];
        } else {
#pragma unroll
            for (int j = 0; j < 8; j++) {
                W[j]     = wih1[k * H + j];       // input side: y0 = S[0..7]
                W[8 + j] = whh1[k * H + j];       // hidden side: h1 = S[8..15]
            }
            bias = bih1[k] + bhh1[k];
        }
    } else if (role == 1) {     // z gate
        const int row = H + k;
        if (layer == 0) {
#pragma unroll
            for (int j = 0; j < 8; j++) W[j] = whh0[row * H + j];
            wx = wih0[row];
            bias = bih0[row] + bhh0[row];
        } else {
#pragma unroll
            for (int j = 0; j < 8; j++) {
                W[j]     = wih1[row * H + j];
                W[8 + j] = whh1[row * H + j];
            }
            bias = bih1[row] + bhh1[row];
        }
    } else if (role == 2) {     // n gate, input side
        const int row = 2 * H + k;
        if (layer == 0) {
            wx = wih0[row];                       // input is scalar x
            bias = bih0[row];
        } else {
#pragma unroll
            for (int j = 0; j < 8; j++) W[j] = wih1[row * H + j];
            bias = bih1[row];
        }
    } else {                    // n gate, hidden side
        const int row = 2 * H + k;
        if (layer == 0) {
#pragma unroll
            for (int j = 0; j < 8; j++) W[j] = whh0[row * H + j];
            bias = bhh0[row];
        } else {
#pragma unroll
            for (int j = 0; j < 8; j++) W[8 + j] = whh1[row * H + j];
            bias = bhh1[row];
        }
    }

    // fold exp base conversion: r,z rows by -log2(e); n rows by 2*log2(e)
    {
        const float scale = (role < 2) ? -1.442695040888963f : 2.885390081777927f;
#pragma unroll
        for (int j = 0; j < 16; j++) W[j] *= scale;
        wx *= scale;
        bias *= scale;
    }

    // ---- launder W through LDS -> clean straight-line VGPR defs ----
#pragma unroll
    for (int j = 0; j < 16; j++) Wbuf[tid][j] = W[j];
    __syncthreads();
    float Wr[16];
    {
        const float4* p = (const float4*)&Wbuf[tid][0];
        float4 q0 = p[0], q1 = p[1], q2 = p[2], q3 = p[3];
        Wr[0]=q0.x;  Wr[1]=q0.y;  Wr[2]=q0.z;  Wr[3]=q0.w;
        Wr[4]=q1.x;  Wr[5]=q1.y;  Wr[6]=q1.z;  Wr[7]=q1.w;
        Wr[8]=q2.x;  Wr[9]=q2.y;  Wr[10]=q2.z; Wr[11]=q2.w;
        Wr[12]=q3.x; Wr[13]=q3.y; Wr[14]=q3.z; Wr[15]=q3.w;
    }

    float hv = (t_first == 0) ? hinit[layer * H + k] : 0.0f;
    float xv = sx[0];
    int s = 0;
    int hrow = 0;

#define STEP_BODY(GUARD, STORE)                                        \
    do {                                                               \
        float S[16];                                                   \
        _Pragma("unroll")                                              \
        for (int j = 0; j < 16; j++) S[j] = bcast(hv, 4 * j);          \
        float xnext = sx[s + 1];                                       \
        float a0 = bias, a1 = 0.0f, a2 = 0.0f, a3 = 0.0f;              \
        _Pragma("unroll")                                              \
        for (int j = 0; j < 4; j++) {                                  \
            a0 = fmaf(Wr[j],      S[j],      a0);                      \
            a1 = fmaf(Wr[4 + j],  S[4 + j],  a1);                      \
            a2 = fmaf(Wr[8 + j],  S[8 + j],  a2);                      \
            a3 = fmaf(Wr[12 + j], S[12 + j], a3);                      \
        }                                                              \
        float a = fmaf(wx, xv, (a0 + a1) + (a2 + a3));                 \
        float eg = exp2_f(a);                                          \
        float g  = fast_rcp(1.0f + eg);      /* role0: r, role1: z */  \
        float rq   = quad_bcast<0>(g);                                 \
        float anhq = quad_bcast<3>(a);                                 \
        float tn = fmaf(rq, anhq, a);        /* role2: tanh input */   \
        float en = exp2_f(tn);                                         \
        float nn = fmaf(-2.0f, fast_rcp(1.0f + en), 1.0f);             \
        float zq = quad_bcast<1>(g);                                   \
        float nq = quad_bcast<2>(nn);                                  \
        float hnew = fmaf(zq, hv - nq, nq);                            \
        hv = (GUARD && sub >= 8) ? hv : hnew;                          \
        if (STORE) { hist[hrow][sub] = hv; hrow++; }                   \
        xv = xnext;                                                    \
    } while (0)

    // s==0: layer1 keeps its init (its y0 input not valid yet)
    STEP_BODY(true, false); s++;
    // warm-up (no history)
    for (; s <= skip; s++) STEP_BODY(false, false);
    // steady: 64 steps, store post-step state; row i = y1(C+i) on cols 8..15
    for (; s <= nsteps; s++) STEP_BODY(false, true);
#undef STEP_BODY

    __syncthreads();
    // ---- parallel readout epilogue: lane t -> out[C + t] ----
    {
        float wl[8];
#pragma unroll
        for (int e = 0; e < 8; e++) wl[e] = wlin[e];
        const float4* hp = (const float4*)&hist[tid][8];
        float4 hA = hp[0], hB = hp[1];
        float ov = blin[0];
        ov = fmaf(wl[0], hA.x, ov); ov = fmaf(wl[1], hA.y, ov);
        ov = fmaf(wl[2], hA.z, ov); ov = fmaf(wl[3], hA.w, ov);
        ov = fmaf(wl[4], hB.x, ov); ov = fmaf(wl[5], hB.y, ov);
        ov = fmaf(wl[6], hB.z, ov); ov = fmaf(wl[7], hB.w, ov);
        out[C + tid] = ov;
    }
}

extern "C" void kernel_launch(void* const* d_in, const int* in_sizes, int n_in,
                              void* d_out, int out_size, void* d_ws, size_t ws_size,
                              hipStream_t stream) {
    (void)in_sizes; (void)n_in; (void)d_ws; (void)ws_size; (void)out_size;
    const float* x    = (const float*)d_in[0];
    const float* h0   = (const float*)d_in[1];
    const float* wih0 = (const float*)d_in[2];
    const float* whh0 = (const float*)d_in[3];
    const float* bih0 = (const float*)d_in[4];
    const float* bhh0 = (const float*)d_in[5];
    const float* wih1 = (const float*)d_in[6];
    const float* whh1 = (const float*)d_in[7];
    const float* bih1 = (const float*)d_in[8];
    const float* bhh1 = (const float*)d_in[9];
    const float* wlin = (const float*)d_in[10];
    const float* blin = (const float*)d_in[11];
    float* out = (float*)d_out;

    gru_chunk_kernel<<<NCHUNK, 64, 0, stream>>>(
        x, h0, wih0, whh0, bih0, bhh0, wih1, whh1, bih1, bhh1, wlin, blin, out);
}

// Round 7
// 36.259 us; speedup vs baseline: 2.0216x; 1.1993x over previous
//
#include <hip/hip_runtime.h>

#define H 8
#define T_LEN 131072
#define CHUNK_L 64
#define WARM 96                    // multiple of 4; steps = WARM + CHUNK_L + 1 = 161
#define NCHUNK (T_LEN / CHUNK_L)   // 2048 blocks -> 2 waves per SIMD
#define SX_LEN 176                 // >= steps + prefetch overrun, zero padded

__device__ __forceinline__ float fast_rcp(float x) { return __builtin_amdgcn_rcpf(x); }
__device__ __forceinline__ float exp2_f(float x) {
#if __has_builtin(__builtin_amdgcn_exp2f)
    return __builtin_amdgcn_exp2f(x);
#else
    return exp2f(x);
#endif
}
__device__ __forceinline__ float bcast(float v, int lane) {   // v_readlane -> SGPR
    return __int_as_float(__builtin_amdgcn_readlane(__float_as_int(v), lane));
}
// broadcast quad-lane Q's value to all 4 lanes of each quad (DPP quad_perm, VALU pipe)
template<int Q>
__device__ __forceinline__ float quad_bcast(float v) {
    return __int_as_float(__builtin_amdgcn_update_dpp(
        0, __float_as_int(v), Q * 0x55, 0xf, 0xf, true));
}

// One wave per chunk (2048 chunks -> 2 waves/SIMD). Lane = unit*4 + role;
// unit = layer*8 + k; role 0:r 1:z 2:n-input 3:n-hidden. Gate rows pre-scaled
// (r,z by -log2e; n by 2*log2e): sigmoid = rcp(1+exp2(a)),
// tanh = 1-2*rcp(1+exp2(r*anh+ani)). Weights laundered through LDS so they
// stay in VGPRs. x consumed from a distance-4 register pipeline (ds_read
// latency off the serial chain); steps unrolled x4. Readout deferred to a
// parallel epilogue via an LDS history of layer-1 state.
__global__ __launch_bounds__(64, 2) void gru_chunk_kernel(
    const float* __restrict__ x, const float* __restrict__ hinit,
    const float* __restrict__ wih0, const float* __restrict__ whh0,
    const float* __restrict__ bih0, const float* __restrict__ bhh0,
    const float* __restrict__ wih1, const float* __restrict__ whh1,
    const float* __restrict__ bih1, const float* __restrict__ bhh1,
    const float* __restrict__ wlin, const float* __restrict__ blin,
    float* __restrict__ out)
{
    const int c = blockIdx.x;
    const int tid = threadIdx.x;
    const int sub = tid >> 2;        // unit 0..15
    const int role = tid & 3;        // r / z / n-input / n-hidden
    const int layer = sub >> 3;
    const int k = sub & 7;

    const int C = c * CHUNK_L;
    int t_first = C - WARM; if (t_first < 0) t_first = 0;
    const int skip = C - t_first;          // 0 (chunk 0) or WARM
    const int nsteps = skip + CHUNK_L;     // last step index

    __shared__ float sx[SX_LEN];
    __shared__ float Wbuf[64][16];
    __shared__ float hist[CHUNK_L][16];

    for (int i = tid; i < SX_LEN; i += 64)
        sx[i] = (i < nsteps) ? x[t_first + i] : 0.0f;

    // ---- branchy per-lane weight build (runs once) ----
    float W[16];
#pragma unroll
    for (int j = 0; j < 16; j++) W[j] = 0.0f;
    float wx = 0.0f, bias;

    if (role == 0) {            // r gate
        if (layer == 0) {
#pragma unroll
            for (int j = 0; j < 8; j++) W[j] = whh0[k * H + j];
            wx = wih0[k];
            bias = bih0[k] + bhh0[k];
        } else {
#pragma unroll
            for (int j = 0; j < 8; j++) {
                W[j]     = wih1[k * H + j];       // input side: y0 = S[0..7]
                W[8 + j] = whh1[k * H + j];       // hidden side: h1 = S[8..15]
            }
            bias = bih1[k] + bhh1[k];
        }
    } else if (role == 1) {     // z gate
        const int row = H + k;
        if (layer == 0) {
#pragma unroll
            for (int j = 0; j < 8; j++) W[j] = whh0[row * H + j];
            wx = wih0[row];
            bias = bih0[row] + bhh0[row];
        } else {
#pragma unroll
            for (int j = 0; j < 8; j++) {
                W[j]     = wih1[row * H + j];
                W[8 + j] = whh1[row * H + j];
            }
            bias = bih1[row] + bhh1[row];
        }
    } else if (role == 2) {     // n gate, input side
        const int row = 2 * H + k;
        if (layer == 0) {
            wx = wih0[row];                       // input is scalar x
            bias = bih0[row];
        } else {
#pragma unroll
            for (int j = 0; j < 8; j++) W[j] = wih1[row * H + j];
            bias = bih1[row];
        }
    } else {                    // n gate, hidden side
        const int row = 2 * H + k;
        if (layer == 0) {
#pragma unroll
            for (int j = 0; j < 8; j++) W[j] = whh0[row * H + j];
            bias = bhh0[row];
        } else {
#pragma unroll
            for (int j = 0; j < 8; j++) W[8 + j] = whh1[row * H + j];
            bias = bhh1[row];
        }
    }

    // fold exp base conversion: r,z rows by -log2(e); n rows by 2*log2(e)
    {
        const float scale = (role < 2) ? -1.442695040888963f : 2.885390081777927f;
#pragma unroll
        for (int j = 0; j < 16; j++) W[j] *= scale;
        wx *= scale;
        bias *= scale;
    }

    // ---- launder W through LDS -> clean straight-line VGPR defs ----
#pragma unroll
    for (int j = 0; j < 16; j++) Wbuf[tid][j] = W[j];
    __syncthreads();
    float Wr[16];
    {
        const float4* p = (const float4*)&Wbuf[tid][0];
        float4 q0 = p[0], q1 = p[1], q2 = p[2], q3 = p[3];
        Wr[0]=q0.x;  Wr[1]=q0.y;  Wr[2]=q0.z;  Wr[3]=q0.w;
        Wr[4]=q1.x;  Wr[5]=q1.y;  Wr[6]=q1.z;  Wr[7]=q1.w;
        Wr[8]=q2.x;  Wr[9]=q2.y;  Wr[10]=q2.z; Wr[11]=q2.w;
        Wr[12]=q3.x; Wr[13]=q3.y; Wr[14]=q3.z; Wr[15]=q3.w;
    }

    float hv = (t_first == 0) ? hinit[layer * H + k] : 0.0f;

#define STEP_BODY(XV, GUARD, STORE, ROW)                               \
    do {                                                               \
        float S[16];                                                   \
        _Pragma("unroll")                                              \
        for (int j = 0; j < 16; j++) S[j] = bcast(hv, 4 * j);          \
        float a0 = bias, a1 = 0.0f, a2 = 0.0f, a3 = 0.0f;              \
        _Pragma("unroll")                                              \
        for (int j = 0; j < 4; j++) {                                  \
            a0 = fmaf(Wr[j],      S[j],      a0);                      \
            a1 = fmaf(Wr[4 + j],  S[4 + j],  a1);                      \
            a2 = fmaf(Wr[8 + j],  S[8 + j],  a2);                      \
            a3 = fmaf(Wr[12 + j], S[12 + j], a3);                      \
        }                                                              \
        float a = fmaf(wx, (XV), (a0 + a1) + (a2 + a3));               \
        float eg = exp2_f(a);                                          \
        float g  = fast_rcp(1.0f + eg);      /* role0: r, role1: z */  \
        float rq   = quad_bcast<0>(g);                                 \
        float anhq = quad_bcast<3>(a);                                 \
        float tn = fmaf(rq, anhq, a);        /* role2: tanh input */   \
        float en = exp2_f(tn);                                         \
        float nn = fmaf(-2.0f, fast_rcp(1.0f + en), 1.0f);             \
        float zq = quad_bcast<1>(g);                                   \
        float nq = quad_bcast<2>(nn);                                  \
        float hnew = fmaf(zq, hv - nq, nq);                            \
        hv = (GUARD && sub >= 8) ? hv : hnew;                          \
        if (STORE) hist[ROW][sub] = hv;                                \
    } while (0)

    // x register pipeline: group [s..s+3] uses xq0..3; next group prefetched
    float xv0 = sx[0];
    float xq0 = sx[1], xq1 = sx[2], xq2 = sx[3], xq3 = sx[4];

    // s == 0: layer1 keeps its init state (its y0 input not valid yet)
    STEP_BODY(xv0, true, false, 0);
    int s = 1;

    // warm-up: WARM steps (multiple of 4), no history
    for (; s + 3 <= skip; s += 4) {
        float xn0 = sx[s + 4], xn1 = sx[s + 5], xn2 = sx[s + 6], xn3 = sx[s + 7];
        STEP_BODY(xq0, false, false, 0);
        STEP_BODY(xq1, false, false, 0);
        STEP_BODY(xq2, false, false, 0);
        STEP_BODY(xq3, false, false, 0);
        xq0 = xn0; xq1 = xn1; xq2 = xn2; xq3 = xn3;
    }
    // steady: 64 steps, store post-step state; row i = y1(C+i) on cols 8..15
    for (; s + 3 <= nsteps; s += 4) {
        float xn0 = sx[s + 4], xn1 = sx[s + 5], xn2 = sx[s + 6], xn3 = sx[s + 7];
        const int row = s - skip - 1;
        STEP_BODY(xq0, false, true, row + 0);
        STEP_BODY(xq1, false, true, row + 1);
        STEP_BODY(xq2, false, true, row + 2);
        STEP_BODY(xq3, false, true, row + 3);
        xq0 = xn0; xq1 = xn1; xq2 = xn2; xq3 = xn3;
    }
#undef STEP_BODY

    __syncthreads();
    // ---- parallel readout epilogue: lane t -> out[C + t] ----
    {
        float wl[8];
#pragma unroll
        for (int e = 0; e < 8; e++) wl[e] = wlin[e];
        const float4* hp = (const float4*)&hist[tid][8];
        float4 hA = hp[0], hB = hp[1];
        float ov = blin[0];
        ov = fmaf(wl[0], hA.x, ov); ov = fmaf(wl[1], hA.y, ov);
        ov = fmaf(wl[2], hA.z, ov); ov = fmaf(wl[3], hA.w, ov);
        ov = fmaf(wl[4], hB.x, ov); ov = fmaf(wl[5], hB.y, ov);
        ov = fmaf(wl[6], hB.z, ov); ov = fmaf(wl[7], hB.w, ov);
        out[C + tid] = ov;
    }
}

extern "C" void kernel_launch(void* const* d_in, const int* in_sizes, int n_in,
                              void* d_out, int out_size, void* d_ws, size_t ws_size,
                              hipStream_t stream) {
    (void)in_sizes; (void)n_in; (void)d_ws; (void)ws_size; (void)out_size;
    const float* x    = (const float*)d_in[0];
    const float* h0   = (const float*)d_in[1];
    const float* wih0 = (const float*)d_in[2];
    const float* whh0 = (const float*)d_in[3];
    const float* bih0 = (const float*)d_in[4];
    const float* bhh0 = (const float*)d_in[5];
    const float* wih1 = (const float*)d_in[6];
    const float* whh1 = (const float*)d_in[7];
    const float* bih1 = (const float*)d_in[8];
    const float* bhh1 = (const float*)d_in[9];
    const float* wlin = (const float*)d_in[10];
    const float* blin = (const float*)d_in[11];
    float* out = (float*)d_out;

    gru_chunk_kernel<<<NCHUNK, 64, 0, stream>>>(
        x, h0, wih0, whh0, bih0, bhh0, wih1, whh1, bih1, bhh1, wlin, blin, out);
}